// Round 13
// baseline (569.568 us; speedup 1.0000x reference)
//
#include <hip/hip_runtime.h>

// ---------------------------------------------------------------------------
// 6-layer GCN. Layer l: y = b + D^-1/2(A+I)D^-1/2 h ; x_next = lrelu(y)
// R12: R11 + TWO dst rows in flight per wave (paired rows d,d+1; adjacent
//      CSR ranges; independent gather chains interleaved -> 8 wide gathers
//      outstanding). Joint loop, then solo drain of the longer row.
// d_ws layout: rowptr[N+1] | dinv[N] | ssrc[E] | bufA[64N] | bufB[64N]
// Build temps alias into bufA (released before layer 0 writes bufA).
// ---------------------------------------------------------------------------

__device__ __forceinline__ float readlane_f(float v, int l) {
    union { float f; int i; } u;
    u.f = v;
    u.i = __builtin_amdgcn_readlane(u.i, l);
    return u.f;
}

// --- pass 1: coarse histogram of dst>>7 into NB buckets ---------------------
__global__ __launch_bounds__(256) void bucket_hist(const int* __restrict__ dst,
                                                   int* __restrict__ ghist,
                                                   int E, int NB) {
    __shared__ int h[1024];
    for (int i = threadIdx.x; i < NB; i += 256) h[i] = 0;
    __syncthreads();
    int i = blockIdx.x * blockDim.x + threadIdx.x;
    int stride = gridDim.x * blockDim.x;
    for (; i < E; i += stride) atomicAdd(&h[dst[i] >> 7], 1);
    __syncthreads();
    for (int j = threadIdx.x; j < NB; j += 256) {
        int c = h[j];
        if (c) atomicAdd(&ghist[j], c);
    }
}

// --- pass 2: exclusive scan of bucket counts (single block, 1024 thr) -------
__global__ void bucket_scan(const int* __restrict__ ghist, int* __restrict__ base,
                            int* __restrict__ cursor, int NB, int E) {
    int tid = threadIdx.x, lane = tid & 63, wid = tid >> 6;
    int v = (tid < NB) ? ghist[tid] : 0;
    int incl = v;
#pragma unroll
    for (int off = 1; off < 64; off <<= 1) {
        int t = __shfl_up(incl, off);
        if (lane >= off) incl += t;
    }
    __shared__ int ws[16];
    if (lane == 63) ws[wid] = incl;
    __syncthreads();
    if (tid == 0) {
        int run = 0;
        for (int i = 0; i < 16; ++i) { int t = ws[i]; ws[i] = run; run += t; }
    }
    __syncthreads();
    int excl = ws[wid] + incl - v;
    if (tid < NB) { base[tid] = excl; cursor[tid] = excl; }
    if (tid == 0) base[NB] = E;
}

// --- pass 3: scatter edges into bucket-sorted (bsrc, bdl) -------------------
__global__ __launch_bounds__(256) void bucket_scatter(
    const int* __restrict__ src, const int* __restrict__ dst,
    int* __restrict__ cursor, int* __restrict__ bsrc,
    unsigned char* __restrict__ bdl, int E, int NB) {
    __shared__ int h[1024];
    __shared__ int rb[1024];
    const int CH = 4096;
    for (int c0 = blockIdx.x * CH; c0 < E; c0 += gridDim.x * CH) {
        int cend = c0 + CH < E ? c0 + CH : E;
        for (int j = threadIdx.x; j < NB; j += 256) h[j] = 0;
        __syncthreads();
        for (int i = c0 + threadIdx.x; i < cend; i += 256)
            atomicAdd(&h[dst[i] >> 7], 1);
        __syncthreads();
        for (int j = threadIdx.x; j < NB; j += 256) {
            int c = h[j];
            rb[j] = c ? atomicAdd(&cursor[j], c) : 0;
            h[j] = 0;
        }
        __syncthreads();
        for (int i = c0 + threadIdx.x; i < cend; i += 256) {
            int d = dst[i];
            int b = d >> 7;
            int p = rb[b] + atomicAdd(&h[b], 1);
            bsrc[p] = src[i];
            bdl[p] = (unsigned char)(d & 127);
        }
        __syncthreads();
    }
}

// --- pass 4: per-bucket CSR finalize: rowptr, dinv, ssrc --------------------
__global__ __launch_bounds__(256) void bucket_finalize(
    const int* __restrict__ base, const int* __restrict__ bsrc,
    const unsigned char* __restrict__ bdl, int* __restrict__ rowptr,
    int* __restrict__ ssrc, float* __restrict__ dinv, int N, int NB, int E) {
    __shared__ int cnt[128];
    __shared__ int cur[128];
    __shared__ int w0sum;
    const int tid = threadIdx.x;
    const int lane = tid & 63;
    for (int b = blockIdx.x; b < NB; b += gridDim.x) {
        const int s = base[b], e = base[b + 1];
        const int d0 = b << 7;
        const int w = (N - d0 < 128) ? (N - d0) : 128;
        if (tid < 128) cnt[tid] = 0;
        __syncthreads();
        for (int i = s + tid; i < e; i += 256) atomicAdd(&cnt[bdl[i]], 1);
        __syncthreads();
        int v = (tid < 128) ? cnt[tid] : 0;
        int incl = v;
#pragma unroll
        for (int off = 1; off < 64; off <<= 1) {
            int t = __shfl_up(incl, off);
            if (lane >= off) incl += t;
        }
        if (tid == 63) w0sum = incl;
        __syncthreads();
        int excl = incl - v + ((tid >= 64 && tid < 128) ? w0sum : 0);
        if (tid < 128) cur[tid] = s + excl;
        if (tid < w) {
            rowptr[d0 + tid] = s + excl;
            dinv[d0 + tid] = rsqrtf((float)(v + 1));   // +1 self loop
        }
        __syncthreads();
        for (int i = s + tid; i < e; i += 256) {
            int p = atomicAdd(&cur[bdl[i]], 1);
            ssrc[p] = bsrc[i];
        }
        __syncthreads();
    }
    if (blockIdx.x == 0 && tid == 0) rowptr[N] = E;
}

// --- dense transform + dinv pre-scale (readlane broadcast, row-major):
//   hs[row,l] = dinv[row] * sum_k in[row,k] * W[k,l]
template <int K>
__global__ __launch_bounds__(256) void gemm_hs(
    const float* __restrict__ in, const float* __restrict__ W,
    const float* __restrict__ dinv, float* __restrict__ hs, int n) {
    const int lane = threadIdx.x & 63;
    const int gw = blockIdx.x * (blockDim.x >> 6) + (threadIdx.x >> 6);
    const int nw = gridDim.x * (blockDim.x >> 6);

    float wreg[K];
#pragma unroll
    for (int k = 0; k < K; ++k) wreg[k] = W[k * 64 + lane];

    for (int row = gw; row < n; row += nw) {
        float xv0 = in[(size_t)row * K + lane];
        float xv1 = 0.f;
        if (K == 128) xv1 = in[(size_t)row * K + 64 + lane];
        float a0 = 0.f, a1 = 0.f, a2 = 0.f, a3 = 0.f;
#pragma unroll
        for (int k = 0; k < 64; k += 4) {
            a0 = fmaf(readlane_f(xv0, k + 0), wreg[k + 0], a0);
            a1 = fmaf(readlane_f(xv0, k + 1), wreg[k + 1], a1);
            a2 = fmaf(readlane_f(xv0, k + 2), wreg[k + 2], a2);
            a3 = fmaf(readlane_f(xv0, k + 3), wreg[k + 3], a3);
        }
        if (K == 128) {
#pragma unroll
            for (int k = 0; k < 64; k += 4) {
                a0 = fmaf(readlane_f(xv1, k + 0), wreg[64 + k + 0], a0);
                a1 = fmaf(readlane_f(xv1, k + 1), wreg[64 + k + 1], a1);
                a2 = fmaf(readlane_f(xv1, k + 2), wreg[64 + k + 2], a2);
                a3 = fmaf(readlane_f(xv1, k + 3), wreg[64 + k + 3], a3);
            }
        }
        float acc = (a0 + a1) + (a2 + a3);
        hs[(size_t)row * 64 + lane] = dinv[row] * acc;
    }
}

// --- aggregation, two rows in flight: wave = rows (d, d+1), 64 lanes =
//     4 edges (g) x 16 float4-chunks (c); masked full-width chunks.
__global__ __launch_bounds__(256) void csr_agg_f4x2(
    const float* __restrict__ hs, const int* __restrict__ rowptr,
    const int* __restrict__ ssrc, const float* __restrict__ dinv,
    const float* __restrict__ b, float* __restrict__ xact, int N) {
    const int lane = threadIdx.x & 63;
    const int g = lane >> 4;         // edge slot 0..3
    const int c = lane & 15;         // float4 chunk 0..15
    const int w = blockIdx.x * 4 + (threadIdx.x >> 6);
    const int nw = gridDim.x * 4;
    const float4 bl = ((const float4*)b)[c];

#define GATHER4(EB, END, LAST, A0, A1)                                          \
    {                                                                           \
        int i0 = (EB) + g, i1 = (EB) + 4 + g, i2 = (EB) + 8 + g, i3 = (EB) + 12 + g; \
        float m0 = i0 < (END) ? 1.f : 0.f;                                      \
        float m1 = i1 < (END) ? 1.f : 0.f;                                      \
        float m2 = i2 < (END) ? 1.f : 0.f;                                      \
        float m3 = i3 < (END) ? 1.f : 0.f;                                      \
        i0 = i0 < (LAST) ? i0 : (LAST);                                         \
        i1 = i1 < (LAST) ? i1 : (LAST);                                         \
        i2 = i2 < (LAST) ? i2 : (LAST);                                         \
        i3 = i3 < (LAST) ? i3 : (LAST);                                         \
        int s0 = __builtin_nontemporal_load(ssrc + i0);                         \
        int s1 = __builtin_nontemporal_load(ssrc + i1);                         \
        int s2 = __builtin_nontemporal_load(ssrc + i2);                         \
        int s3 = __builtin_nontemporal_load(ssrc + i3);                         \
        float4 v0 = ((const float4*)(hs + (size_t)s0 * 64))[c];                 \
        float4 v1 = ((const float4*)(hs + (size_t)s1 * 64))[c];                 \
        float4 v2 = ((const float4*)(hs + (size_t)s2 * 64))[c];                 \
        float4 v3 = ((const float4*)(hs + (size_t)s3 * 64))[c];                 \
        A0.x = fmaf(m0, v0.x, A0.x); A0.y = fmaf(m0, v0.y, A0.y);               \
        A0.z = fmaf(m0, v0.z, A0.z); A0.w = fmaf(m0, v0.w, A0.w);               \
        A1.x = fmaf(m1, v1.x, A1.x); A1.y = fmaf(m1, v1.y, A1.y);               \
        A1.z = fmaf(m1, v1.z, A1.z); A1.w = fmaf(m1, v1.w, A1.w);               \
        A0.x = fmaf(m2, v2.x, A0.x); A0.y = fmaf(m2, v2.y, A0.y);               \
        A0.z = fmaf(m2, v2.z, A0.z); A0.w = fmaf(m2, v2.w, A0.w);               \
        A1.x = fmaf(m3, v3.x, A1.x); A1.y = fmaf(m3, v3.y, A1.y);               \
        A1.z = fmaf(m3, v3.z, A1.z); A1.w = fmaf(m3, v3.w, A1.w);               \
    }

#define EPILOG(D, AA, AB)                                                       \
    {                                                                           \
        float4 acc = make_float4(AA.x + AB.x, AA.y + AB.y, AA.z + AB.z, AA.w + AB.w); \
        acc.x += __shfl_xor(acc.x, 16); acc.y += __shfl_xor(acc.y, 16);         \
        acc.z += __shfl_xor(acc.z, 16); acc.w += __shfl_xor(acc.w, 16);         \
        acc.x += __shfl_xor(acc.x, 32); acc.y += __shfl_xor(acc.y, 32);         \
        acc.z += __shfl_xor(acc.z, 32); acc.w += __shfl_xor(acc.w, 32);         \
        const float di = dinv[D];                                               \
        float4 y;                                                               \
        y.x = fmaf(di, acc.x, bl.x); y.y = fmaf(di, acc.y, bl.y);               \
        y.z = fmaf(di, acc.z, bl.z); y.w = fmaf(di, acc.w, bl.w);               \
        y.x = y.x >= 0.f ? y.x : 0.2f * y.x;                                    \
        y.y = y.y >= 0.f ? y.y : 0.2f * y.y;                                    \
        y.z = y.z >= 0.f ? y.z : 0.2f * y.z;                                    \
        y.w = y.w >= 0.f ? y.w : 0.2f * y.w;                                    \
        if (g == 0) ((float4*)(xact + (size_t)(D) * 64))[c] = y;                \
    }

    for (int d = w * 2; d < N; d += nw * 2) {
        const bool two = (d + 1 < N);
        int p0 = __builtin_amdgcn_readfirstlane(rowptr[d]);
        int p1 = __builtin_amdgcn_readfirstlane(rowptr[d + 1]);
        int p2 = two ? __builtin_amdgcn_readfirstlane(rowptr[d + 2]) : p1;
        int e0 = p0, e1 = p1;
        const int last0 = p1 - 1, last1 = p2 - 1;
        float4 z = make_float4(0.f, 0.f, 0.f, 0.f);
        float4 aA0 = z, aA1 = z, aB0 = z, aB1 = z;
        if (g == 0) {
            aA0 = ((const float4*)(hs + (size_t)d * 64))[c];          // self loop
            if (two) aB0 = ((const float4*)(hs + (size_t)(d + 1) * 64))[c];
        }
        // joint phase: both rows issue a full-width chunk (8 gathers in flight)
        while (e0 < p1 && e1 < p2) {
            GATHER4(e0, p1, last0, aA0, aA1);
            GATHER4(e1, p2, last1, aB0, aB1);
            e0 += 16; e1 += 16;
        }
        // solo drains
        while (e0 < p1) { GATHER4(e0, p1, last0, aA0, aA1); e0 += 16; }
        while (e1 < p2) { GATHER4(e1, p2, last1, aB0, aB1); e1 += 16; }
        EPILOG(d, aA0, aA1);
        if (two) EPILOG(d + 1, aB0, aB1);
    }
#undef GATHER4
#undef EPILOG
}

// --- final layer gemm: pre-activated x -> W5[64,4] -> dinv scale ------------
__global__ __launch_bounds__(256) void gemm4_hs(
    const float* __restrict__ xact, const float* __restrict__ W,  // [64,4]
    const float* __restrict__ dinv, float* __restrict__ hs4, int n) {
    int i = blockIdx.x * blockDim.x + threadIdx.x;
    int stride = gridDim.x * blockDim.x;
    for (; i < n; i += stride) {
        const float4* xr = (const float4*)(xact + (size_t)i * 64);
        float a0 = 0.f, a1 = 0.f, a2 = 0.f, a3 = 0.f;
#pragma unroll
        for (int k4 = 0; k4 < 16; ++k4) {
            float4 xv = xr[k4];
            int k = k4 * 4;
            a0 = fmaf(xv.x, W[(k + 0) * 4 + 0], a0); a1 = fmaf(xv.x, W[(k + 0) * 4 + 1], a1);
            a2 = fmaf(xv.x, W[(k + 0) * 4 + 2], a2); a3 = fmaf(xv.x, W[(k + 0) * 4 + 3], a3);
            a0 = fmaf(xv.y, W[(k + 1) * 4 + 0], a0); a1 = fmaf(xv.y, W[(k + 1) * 4 + 1], a1);
            a2 = fmaf(xv.y, W[(k + 1) * 4 + 2], a2); a3 = fmaf(xv.y, W[(k + 1) * 4 + 3], a3);
            a0 = fmaf(xv.z, W[(k + 2) * 4 + 0], a0); a1 = fmaf(xv.z, W[(k + 2) * 4 + 1], a1);
            a2 = fmaf(xv.z, W[(k + 2) * 4 + 2], a2); a3 = fmaf(xv.z, W[(k + 2) * 4 + 3], a3);
            a0 = fmaf(xv.w, W[(k + 3) * 4 + 0], a0); a1 = fmaf(xv.w, W[(k + 3) * 4 + 1], a1);
            a2 = fmaf(xv.w, W[(k + 3) * 4 + 2], a2); a3 = fmaf(xv.w, W[(k + 3) * 4 + 3], a3);
        }
        float di = dinv[i];
        ((float4*)hs4)[i] = make_float4(di * a0, di * a1, di * a2, di * a3);
    }
}

// --- final aggregation over pre-scaled hs4: out = b + dinv[d]*(self + sum) --
__global__ __launch_bounds__(256) void csr_agg4(
    const float* __restrict__ hs4, const int* __restrict__ rowptr,
    const int* __restrict__ ssrc, const float* __restrict__ dinv,
    const float* __restrict__ b, float* __restrict__ out, int n) {
    int i = blockIdx.x * blockDim.x + threadIdx.x;
    int stride = gridDim.x * blockDim.x;
    float b0 = b[0], b1 = b[1], b2 = b[2], b3 = b[3];
    for (; i < n; i += stride) {
        float4 hv = ((const float4*)hs4)[i];
        float a0 = hv.x, a1 = hv.y, a2 = hv.z, a3 = hv.w;   // self loop
        int e = rowptr[i], end = rowptr[i + 1];
        for (; e < end; ++e) {
            int s = ssrc[e];
            float4 v = ((const float4*)hs4)[s];
            a0 += v.x; a1 += v.y; a2 += v.z; a3 += v.w;
        }
        float di = dinv[i];
        ((float4*)out)[i] = make_float4(fmaf(di, a0, b0), fmaf(di, a1, b1),
                                        fmaf(di, a2, b2), fmaf(di, a3, b3));
    }
}

static inline size_t al64(size_t x) { return (x + 63) & ~(size_t)63; }

extern "C" void kernel_launch(void* const* d_in, const int* in_sizes, int n_in,
                              void* d_out, int out_size, void* d_ws, size_t ws_size,
                              hipStream_t stream) {
    const float* x  = (const float*)d_in[0];
    const int* ei   = (const int*)d_in[1];
    const float* W0 = (const float*)d_in[2];
    const float* b0 = (const float*)d_in[3];
    const float* W1 = (const float*)d_in[4];
    const float* b1 = (const float*)d_in[5];
    const float* W2 = (const float*)d_in[6];
    const float* b2 = (const float*)d_in[7];
    const float* W3 = (const float*)d_in[8];
    const float* b3 = (const float*)d_in[9];
    const float* W4 = (const float*)d_in[10];
    const float* b4 = (const float*)d_in[11];
    const float* W5 = (const float*)d_in[12];
    const float* b5 = (const float*)d_in[13];

    const int N = in_sizes[0] / 128;
    const int E = in_sizes[1] / 2;
    const int* src  = ei;       // edge_index[0] = message sources
    const int* dstp = ei + E;   // edge_index[1] = aggregation targets
    const int NB = (N + 127) >> 7;   // dst buckets of 128 ids (NB <= 1024)

    float* ws = (float*)d_ws;
    size_t off = 0;
    int*   rowptr = (int*)(ws + off);   off += al64((size_t)N + 1);
    float* dinv   = ws + off;           off += al64((size_t)N);
    int*   ssrc   = (int*)(ws + off);   off += al64((size_t)E);
    float* bufA   = ws + off;           off += (size_t)64 * N;
    float* bufB   = ws + off;

    // build temps alias into bufA (released before layer 0 writes bufA)
    int* ghist = (int*)bufA;                       // [1024]
    int* bbase = ghist + 1024;                     // [NB+1]
    int* bcur  = bbase + 1088;                     // [NB]
    int* bsrc  = (int*)(bufA + 4096);              // [E]
    unsigned char* bdl = (unsigned char*)(bsrc + E);  // [E]

    // ---- graph build (bucketed counting sort) ----
    hipMemsetAsync(ghist, 0, 1024 * sizeof(int), stream);
    bucket_hist<<<391, 256, 0, stream>>>(dstp, ghist, E, NB);
    bucket_scan<<<1, 1024, 0, stream>>>(ghist, bbase, bcur, NB, E);
    bucket_scatter<<<391, 256, 0, stream>>>(src, dstp, bcur, bsrc, bdl, E, NB);
    bucket_finalize<<<NB, 256, 0, stream>>>(bbase, bsrc, bdl, rowptr, ssrc, dinv, N, NB, E);

    const int AGG_BLOCKS = 4096;

    // ---- layer 0: x[N,128] -> hs0 ----
    gemm_hs<128><<<2048, 256, 0, stream>>>(x, W0, dinv, bufA, N);
    csr_agg_f4x2<<<AGG_BLOCKS, 256, 0, stream>>>(bufA, rowptr, ssrc, dinv, b0, bufB, N);

    // ---- layers 1-4 (xact in bufB -> hs in bufA -> xact in bufB) ----
    const float* Ws[4] = {W1, W2, W3, W4};
    const float* bs[4] = {b1, b2, b3, b4};
    for (int l = 0; l < 4; ++l) {
        gemm_hs<64><<<2048, 256, 0, stream>>>(bufB, Ws[l], dinv, bufA, N);
        csr_agg_f4x2<<<AGG_BLOCKS, 256, 0, stream>>>(bufA, rowptr, ssrc, dinv, bs[l], bufB, N);
    }

    // ---- layer 5: xact -> hs4[N,4] -> out ----
    gemm4_hs<<<1024, 256, 0, stream>>>(bufB, W5, dinv, bufA, N);
    csr_agg4<<<1024, 256, 0, stream>>>(bufA, rowptr, ssrc, dinv, b5, (float*)d_out, N);
}

// Round 14
// 561.282 us; speedup vs baseline: 1.0148x; 1.0148x over previous
//
#include <hip/hip_runtime.h>

// ---------------------------------------------------------------------------
// 6-layer GCN. Layer l: y = b + D^-1/2(A+I)D^-1/2 h ; x_next = lrelu(y)
// R13: agg = R11's csr_agg_f4 (best known: 63 us, 28 VGPR, occ 70%).
//      gemm = packed-math: float2 ext-vectors over adjacent k so the
//      compiler emits v_pk_fma_f32 (2 fp32 FMA / inst) against an SGPR-pair
//      broadcast from 2 readlanes. Halves GEMM VALU instruction count.
// d_ws layout: rowptr[N+1] | dinv[N] | ssrc[E] | bufA[64N] | bufB[64N]
// Build temps alias into bufA (released before layer 0 writes bufA).
// ---------------------------------------------------------------------------

typedef float f32x2 __attribute__((ext_vector_type(2)));

__device__ __forceinline__ float readlane_f(float v, int l) {
    union { float f; int i; } u;
    u.f = v;
    u.i = __builtin_amdgcn_readlane(u.i, l);
    return u.f;
}

// --- pass 1: coarse histogram of dst>>7 into NB buckets ---------------------
__global__ __launch_bounds__(256) void bucket_hist(const int* __restrict__ dst,
                                                   int* __restrict__ ghist,
                                                   int E, int NB) {
    __shared__ int h[1024];
    for (int i = threadIdx.x; i < NB; i += 256) h[i] = 0;
    __syncthreads();
    int i = blockIdx.x * blockDim.x + threadIdx.x;
    int stride = gridDim.x * blockDim.x;
    for (; i < E; i += stride) atomicAdd(&h[dst[i] >> 7], 1);
    __syncthreads();
    for (int j = threadIdx.x; j < NB; j += 256) {
        int c = h[j];
        if (c) atomicAdd(&ghist[j], c);
    }
}

// --- pass 2: exclusive scan of bucket counts (single block, 1024 thr) -------
__global__ void bucket_scan(const int* __restrict__ ghist, int* __restrict__ base,
                            int* __restrict__ cursor, int NB, int E) {
    int tid = threadIdx.x, lane = tid & 63, wid = tid >> 6;
    int v = (tid < NB) ? ghist[tid] : 0;
    int incl = v;
#pragma unroll
    for (int off = 1; off < 64; off <<= 1) {
        int t = __shfl_up(incl, off);
        if (lane >= off) incl += t;
    }
    __shared__ int ws[16];
    if (lane == 63) ws[wid] = incl;
    __syncthreads();
    if (tid == 0) {
        int run = 0;
        for (int i = 0; i < 16; ++i) { int t = ws[i]; ws[i] = run; run += t; }
    }
    __syncthreads();
    int excl = ws[wid] + incl - v;
    if (tid < NB) { base[tid] = excl; cursor[tid] = excl; }
    if (tid == 0) base[NB] = E;
}

// --- pass 3: scatter edges into bucket-sorted (bsrc, bdl) -------------------
__global__ __launch_bounds__(256) void bucket_scatter(
    const int* __restrict__ src, const int* __restrict__ dst,
    int* __restrict__ cursor, int* __restrict__ bsrc,
    unsigned char* __restrict__ bdl, int E, int NB) {
    __shared__ int h[1024];
    __shared__ int rb[1024];
    const int CH = 4096;
    for (int c0 = blockIdx.x * CH; c0 < E; c0 += gridDim.x * CH) {
        int cend = c0 + CH < E ? c0 + CH : E;
        for (int j = threadIdx.x; j < NB; j += 256) h[j] = 0;
        __syncthreads();
        for (int i = c0 + threadIdx.x; i < cend; i += 256)
            atomicAdd(&h[dst[i] >> 7], 1);
        __syncthreads();
        for (int j = threadIdx.x; j < NB; j += 256) {
            int c = h[j];
            rb[j] = c ? atomicAdd(&cursor[j], c) : 0;
            h[j] = 0;
        }
        __syncthreads();
        for (int i = c0 + threadIdx.x; i < cend; i += 256) {
            int d = dst[i];
            int b = d >> 7;
            int p = rb[b] + atomicAdd(&h[b], 1);
            bsrc[p] = src[i];
            bdl[p] = (unsigned char)(d & 127);
        }
        __syncthreads();
    }
}

// --- pass 4: per-bucket CSR finalize: rowptr, dinv, ssrc --------------------
__global__ __launch_bounds__(256) void bucket_finalize(
    const int* __restrict__ base, const int* __restrict__ bsrc,
    const unsigned char* __restrict__ bdl, int* __restrict__ rowptr,
    int* __restrict__ ssrc, float* __restrict__ dinv, int N, int NB, int E) {
    __shared__ int cnt[128];
    __shared__ int cur[128];
    __shared__ int w0sum;
    const int tid = threadIdx.x;
    const int lane = tid & 63;
    for (int b = blockIdx.x; b < NB; b += gridDim.x) {
        const int s = base[b], e = base[b + 1];
        const int d0 = b << 7;
        const int w = (N - d0 < 128) ? (N - d0) : 128;
        if (tid < 128) cnt[tid] = 0;
        __syncthreads();
        for (int i = s + tid; i < e; i += 256) atomicAdd(&cnt[bdl[i]], 1);
        __syncthreads();
        int v = (tid < 128) ? cnt[tid] : 0;
        int incl = v;
#pragma unroll
        for (int off = 1; off < 64; off <<= 1) {
            int t = __shfl_up(incl, off);
            if (lane >= off) incl += t;
        }
        if (tid == 63) w0sum = incl;
        __syncthreads();
        int excl = incl - v + ((tid >= 64 && tid < 128) ? w0sum : 0);
        if (tid < 128) cur[tid] = s + excl;
        if (tid < w) {
            rowptr[d0 + tid] = s + excl;
            dinv[d0 + tid] = rsqrtf((float)(v + 1));   // +1 self loop
        }
        __syncthreads();
        for (int i = s + tid; i < e; i += 256) {
            int p = atomicAdd(&cur[bdl[i]], 1);
            ssrc[p] = bsrc[i];
        }
        __syncthreads();
    }
    if (blockIdx.x == 0 && tid == 0) rowptr[N] = E;
}

// --- dense transform + dinv pre-scale, packed-math (v_pk_fma_f32):
//   hs[row,l] = dinv[row] * sum_k in[row,k] * W[k,l]
template <int K>
__global__ __launch_bounds__(256) void gemm_hs(
    const float* __restrict__ in, const float* __restrict__ W,
    const float* __restrict__ dinv, float* __restrict__ hs, int n) {
    const int lane = threadIdx.x & 63;
    const int gw = blockIdx.x * (blockDim.x >> 6) + (threadIdx.x >> 6);
    const int nw = gridDim.x * (blockDim.x >> 6);

    f32x2 wreg[K / 2];
#pragma unroll
    for (int j = 0; j < K / 2; ++j) {
        wreg[j].x = W[(2 * j) * 64 + lane];
        wreg[j].y = W[(2 * j + 1) * 64 + lane];
    }

    for (int row = gw; row < n; row += nw) {
        float xv0 = in[(size_t)row * K + lane];
        float xv1 = 0.f;
        if (K == 128) xv1 = in[(size_t)row * K + 64 + lane];
        f32x2 a0 = {0.f, 0.f}, a1 = {0.f, 0.f};
#pragma unroll
        for (int j = 0; j < 32; j += 2) {
            f32x2 xb0, xb1;
            xb0.x = readlane_f(xv0, 2 * j);
            xb0.y = readlane_f(xv0, 2 * j + 1);
            xb1.x = readlane_f(xv0, 2 * j + 2);
            xb1.y = readlane_f(xv0, 2 * j + 3);
            a0 += xb0 * wreg[j];        // -> v_pk_fma_f32 (fp-contract)
            a1 += xb1 * wreg[j + 1];
        }
        if (K == 128) {
#pragma unroll
            for (int j = 0; j < 32; j += 2) {
                f32x2 xb0, xb1;
                xb0.x = readlane_f(xv1, 2 * j);
                xb0.y = readlane_f(xv1, 2 * j + 1);
                xb1.x = readlane_f(xv1, 2 * j + 2);
                xb1.y = readlane_f(xv1, 2 * j + 3);
                a0 += xb0 * wreg[32 + j];
                a1 += xb1 * wreg[32 + j + 1];
            }
        }
        float acc = (a0.x + a0.y) + (a1.x + a1.y);
        hs[(size_t)row * 64 + lane] = dinv[row] * acc;
    }
}

// --- aggregation with wide masked gathers (R11 exact): wave = dst row,
//     64 lanes = 4 edges (g) x 16 float4-chunks (c); no serial tail.
__global__ __launch_bounds__(256) void csr_agg_f4(
    const float* __restrict__ hs, const int* __restrict__ rowptr,
    const int* __restrict__ ssrc, const float* __restrict__ dinv,
    const float* __restrict__ b, float* __restrict__ xact, int N) {
    const int lane = threadIdx.x & 63;
    const int g = lane >> 4;         // edge slot 0..3
    const int c = lane & 15;         // float4 chunk 0..15
    const int w = blockIdx.x * 4 + (threadIdx.x >> 6);
    const int nw = gridDim.x * 4;
    const float4 bl = ((const float4*)b)[c];

    for (int d = w; d < N; d += nw) {
        int e = __builtin_amdgcn_readfirstlane(rowptr[d]);
        const int end = __builtin_amdgcn_readfirstlane(rowptr[d + 1]);
        const int last = end - 1;
        float4 a0 = make_float4(0.f, 0.f, 0.f, 0.f), a1 = a0;
        if (g == 0) a0 = ((const float4*)(hs + (size_t)d * 64))[c];  // self loop
        for (; e < end; e += 16) {
            int i0 = e + g, i1 = e + 4 + g, i2 = e + 8 + g, i3 = e + 12 + g;
            float m0 = i0 < end ? 1.f : 0.f;
            float m1 = i1 < end ? 1.f : 0.f;
            float m2 = i2 < end ? 1.f : 0.f;
            float m3 = i3 < end ? 1.f : 0.f;
            i0 = i0 < last ? i0 : last;
            i1 = i1 < last ? i1 : last;
            i2 = i2 < last ? i2 : last;
            i3 = i3 < last ? i3 : last;
            int s0 = __builtin_nontemporal_load(ssrc + i0);
            int s1 = __builtin_nontemporal_load(ssrc + i1);
            int s2 = __builtin_nontemporal_load(ssrc + i2);
            int s3 = __builtin_nontemporal_load(ssrc + i3);
            float4 v0 = ((const float4*)(hs + (size_t)s0 * 64))[c];
            float4 v1 = ((const float4*)(hs + (size_t)s1 * 64))[c];
            float4 v2 = ((const float4*)(hs + (size_t)s2 * 64))[c];
            float4 v3 = ((const float4*)(hs + (size_t)s3 * 64))[c];
            a0.x = fmaf(m0, v0.x, a0.x); a0.y = fmaf(m0, v0.y, a0.y);
            a0.z = fmaf(m0, v0.z, a0.z); a0.w = fmaf(m0, v0.w, a0.w);
            a1.x = fmaf(m1, v1.x, a1.x); a1.y = fmaf(m1, v1.y, a1.y);
            a1.z = fmaf(m1, v1.z, a1.z); a1.w = fmaf(m1, v1.w, a1.w);
            a0.x = fmaf(m2, v2.x, a0.x); a0.y = fmaf(m2, v2.y, a0.y);
            a0.z = fmaf(m2, v2.z, a0.z); a0.w = fmaf(m2, v2.w, a0.w);
            a1.x = fmaf(m3, v3.x, a1.x); a1.y = fmaf(m3, v3.y, a1.y);
            a1.z = fmaf(m3, v3.z, a1.z); a1.w = fmaf(m3, v3.w, a1.w);
        }
        float4 acc = make_float4(a0.x + a1.x, a0.y + a1.y, a0.z + a1.z, a0.w + a1.w);
        // reduce over the 4 edge groups (lane ^16, ^32)
        acc.x += __shfl_xor(acc.x, 16); acc.y += __shfl_xor(acc.y, 16);
        acc.z += __shfl_xor(acc.z, 16); acc.w += __shfl_xor(acc.w, 16);
        acc.x += __shfl_xor(acc.x, 32); acc.y += __shfl_xor(acc.y, 32);
        acc.z += __shfl_xor(acc.z, 32); acc.w += __shfl_xor(acc.w, 32);
        const float di = dinv[d];
        float4 y;
        y.x = fmaf(di, acc.x, bl.x); y.y = fmaf(di, acc.y, bl.y);
        y.z = fmaf(di, acc.z, bl.z); y.w = fmaf(di, acc.w, bl.w);
        y.x = y.x >= 0.f ? y.x : 0.2f * y.x;
        y.y = y.y >= 0.f ? y.y : 0.2f * y.y;
        y.z = y.z >= 0.f ? y.z : 0.2f * y.z;
        y.w = y.w >= 0.f ? y.w : 0.2f * y.w;
        if (g == 0) ((float4*)(xact + (size_t)d * 64))[c] = y;
    }
}

// --- final layer gemm: pre-activated x -> W5[64,4] -> dinv scale ------------
__global__ __launch_bounds__(256) void gemm4_hs(
    const float* __restrict__ xact, const float* __restrict__ W,  // [64,4]
    const float* __restrict__ dinv, float* __restrict__ hs4, int n) {
    int i = blockIdx.x * blockDim.x + threadIdx.x;
    int stride = gridDim.x * blockDim.x;
    for (; i < n; i += stride) {
        const float4* xr = (const float4*)(xact + (size_t)i * 64);
        float a0 = 0.f, a1 = 0.f, a2 = 0.f, a3 = 0.f;
#pragma unroll
        for (int k4 = 0; k4 < 16; ++k4) {
            float4 xv = xr[k4];
            int k = k4 * 4;
            a0 = fmaf(xv.x, W[(k + 0) * 4 + 0], a0); a1 = fmaf(xv.x, W[(k + 0) * 4 + 1], a1);
            a2 = fmaf(xv.x, W[(k + 0) * 4 + 2], a2); a3 = fmaf(xv.x, W[(k + 0) * 4 + 3], a3);
            a0 = fmaf(xv.y, W[(k + 1) * 4 + 0], a0); a1 = fmaf(xv.y, W[(k + 1) * 4 + 1], a1);
            a2 = fmaf(xv.y, W[(k + 1) * 4 + 2], a2); a3 = fmaf(xv.y, W[(k + 1) * 4 + 3], a3);
            a0 = fmaf(xv.z, W[(k + 2) * 4 + 0], a0); a1 = fmaf(xv.z, W[(k + 2) * 4 + 1], a1);
            a2 = fmaf(xv.z, W[(k + 2) * 4 + 2], a2); a3 = fmaf(xv.z, W[(k + 2) * 4 + 3], a3);
            a0 = fmaf(xv.w, W[(k + 3) * 4 + 0], a0); a1 = fmaf(xv.w, W[(k + 3) * 4 + 1], a1);
            a2 = fmaf(xv.w, W[(k + 3) * 4 + 2], a2); a3 = fmaf(xv.w, W[(k + 3) * 4 + 3], a3);
        }
        float di = dinv[i];
        ((float4*)hs4)[i] = make_float4(di * a0, di * a1, di * a2, di * a3);
    }
}

// --- final aggregation over pre-scaled hs4: out = b + dinv[d]*(self + sum) --
__global__ __launch_bounds__(256) void csr_agg4(
    const float* __restrict__ hs4, const int* __restrict__ rowptr,
    const int* __restrict__ ssrc, const float* __restrict__ dinv,
    const float* __restrict__ b, float* __restrict__ out, int n) {
    int i = blockIdx.x * blockDim.x + threadIdx.x;
    int stride = gridDim.x * blockDim.x;
    float b0 = b[0], b1 = b[1], b2 = b[2], b3 = b[3];
    for (; i < n; i += stride) {
        float4 hv = ((const float4*)hs4)[i];
        float a0 = hv.x, a1 = hv.y, a2 = hv.z, a3 = hv.w;   // self loop
        int e = rowptr[i], end = rowptr[i + 1];
        for (; e < end; ++e) {
            int s = ssrc[e];
            float4 v = ((const float4*)hs4)[s];
            a0 += v.x; a1 += v.y; a2 += v.z; a3 += v.w;
        }
        float di = dinv[i];
        ((float4*)out)[i] = make_float4(fmaf(di, a0, b0), fmaf(di, a1, b1),
                                        fmaf(di, a2, b2), fmaf(di, a3, b3));
    }
}

static inline size_t al64(size_t x) { return (x + 63) & ~(size_t)63; }

extern "C" void kernel_launch(void* const* d_in, const int* in_sizes, int n_in,
                              void* d_out, int out_size, void* d_ws, size_t ws_size,
                              hipStream_t stream) {
    const float* x  = (const float*)d_in[0];
    const int* ei   = (const int*)d_in[1];
    const float* W0 = (const float*)d_in[2];
    const float* b0 = (const float*)d_in[3];
    const float* W1 = (const float*)d_in[4];
    const float* b1 = (const float*)d_in[5];
    const float* W2 = (const float*)d_in[6];
    const float* b2 = (const float*)d_in[7];
    const float* W3 = (const float*)d_in[8];
    const float* b3 = (const float*)d_in[9];
    const float* W4 = (const float*)d_in[10];
    const float* b4 = (const float*)d_in[11];
    const float* W5 = (const float*)d_in[12];
    const float* b5 = (const float*)d_in[13];

    const int N = in_sizes[0] / 128;
    const int E = in_sizes[1] / 2;
    const int* src  = ei;       // edge_index[0] = message sources
    const int* dstp = ei + E;   // edge_index[1] = aggregation targets
    const int NB = (N + 127) >> 7;   // dst buckets of 128 ids (NB <= 1024)

    float* ws = (float*)d_ws;
    size_t off = 0;
    int*   rowptr = (int*)(ws + off);   off += al64((size_t)N + 1);
    float* dinv   = ws + off;           off += al64((size_t)N);
    int*   ssrc   = (int*)(ws + off);   off += al64((size_t)E);
    float* bufA   = ws + off;           off += (size_t)64 * N;
    float* bufB   = ws + off;

    // build temps alias into bufA (released before layer 0 writes bufA)
    int* ghist = (int*)bufA;                       // [1024]
    int* bbase = ghist + 1024;                     // [NB+1]
    int* bcur  = bbase + 1088;                     // [NB]
    int* bsrc  = (int*)(bufA + 4096);              // [E]
    unsigned char* bdl = (unsigned char*)(bsrc + E);  // [E]

    // ---- graph build (bucketed counting sort) ----
    hipMemsetAsync(ghist, 0, 1024 * sizeof(int), stream);
    bucket_hist<<<391, 256, 0, stream>>>(dstp, ghist, E, NB);
    bucket_scan<<<1, 1024, 0, stream>>>(ghist, bbase, bcur, NB, E);
    bucket_scatter<<<391, 256, 0, stream>>>(src, dstp, bcur, bsrc, bdl, E, NB);
    bucket_finalize<<<NB, 256, 0, stream>>>(bbase, bsrc, bdl, rowptr, ssrc, dinv, N, NB, E);

    const int AGG_BLOCKS = 4096;

    // ---- layer 0: x[N,128] -> hs0 ----
    gemm_hs<128><<<2048, 256, 0, stream>>>(x, W0, dinv, bufA, N);
    csr_agg_f4<<<AGG_BLOCKS, 256, 0, stream>>>(bufA, rowptr, ssrc, dinv, b0, bufB, N);

    // ---- layers 1-4 (xact in bufB -> hs in bufA -> xact in bufB) ----
    const float* Ws[4] = {W1, W2, W3, W4};
    const float* bs[4] = {b1, b2, b3, b4};
    for (int l = 0; l < 4; ++l) {
        gemm_hs<64><<<2048, 256, 0, stream>>>(bufB, Ws[l], dinv, bufA, N);
        csr_agg_f4<<<AGG_BLOCKS, 256, 0, stream>>>(bufA, rowptr, ssrc, dinv, bs[l], bufB, N);
    }

    // ---- layer 5: xact -> hs4[N,4] -> out ----
    gemm4_hs<<<1024, 256, 0, stream>>>(bufB, W5, dinv, bufA, N);
    csr_agg4<<<1024, 256, 0, stream>>>(bufA, rowptr, ssrc, dinv, b5, (float*)d_out, N);
}

// Round 15
// 557.035 us; speedup vs baseline: 1.0225x; 1.0076x over previous
//
#include <hip/hip_runtime.h>

// ---------------------------------------------------------------------------
// 6-layer GCN. Layer l: y = b + D^-1/2(A+I)D^-1/2 h ; x_next = lrelu(y)
// R14: R11-exact compute path (gemm readlane-fma, csr_agg_f4 wide masked
//      gathers, lrelu-in-agg, prescaled hs). Build diet:
//      - scatter writes ONE packed u32 (dl<<20|src) instead of 4B+1B streams
//      - hist 784 blocks with int4 reads; scatter 782 blocks (CH=2048)
// d_ws layout: rowptr[N+1] | dinv[N] | ssrc[E] | bufA[64N] | bufB[64N]
// Build temps alias into bufA (released before layer 0 writes bufA).
// ---------------------------------------------------------------------------

__device__ __forceinline__ float readlane_f(float v, int l) {
    union { float f; int i; } u;
    u.f = v;
    u.i = __builtin_amdgcn_readlane(u.i, l);
    return u.f;
}

// --- pass 1: coarse histogram of dst>>7 into NB buckets (int4 reads) --------
__global__ __launch_bounds__(256) void bucket_hist(const int* __restrict__ dst,
                                                   int* __restrict__ ghist,
                                                   int E, int NB) {
    __shared__ int h[1024];
    for (int i = threadIdx.x; i < NB; i += 256) h[i] = 0;
    __syncthreads();
    const int E4 = E >> 2;
    int i = blockIdx.x * blockDim.x + threadIdx.x;
    int stride = gridDim.x * blockDim.x;
    for (; i < E4; i += stride) {
        int4 v = ((const int4*)dst)[i];
        atomicAdd(&h[v.x >> 7], 1);
        atomicAdd(&h[v.y >> 7], 1);
        atomicAdd(&h[v.z >> 7], 1);
        atomicAdd(&h[v.w >> 7], 1);
    }
    // tail
    if (blockIdx.x == 0) {
        for (int t = (E4 << 2) + threadIdx.x; t < E; t += 256)
            atomicAdd(&h[dst[t] >> 7], 1);
    }
    __syncthreads();
    for (int j = threadIdx.x; j < NB; j += 256) {
        int c = h[j];
        if (c) atomicAdd(&ghist[j], c);
    }
}

// --- pass 2: exclusive scan of bucket counts (single block, 1024 thr) -------
__global__ void bucket_scan(const int* __restrict__ ghist, int* __restrict__ base,
                            int* __restrict__ cursor, int NB, int E) {
    int tid = threadIdx.x, lane = tid & 63, wid = tid >> 6;
    int v = (tid < NB) ? ghist[tid] : 0;
    int incl = v;
#pragma unroll
    for (int off = 1; off < 64; off <<= 1) {
        int t = __shfl_up(incl, off);
        if (lane >= off) incl += t;
    }
    __shared__ int ws[16];
    if (lane == 63) ws[wid] = incl;
    __syncthreads();
    if (tid == 0) {
        int run = 0;
        for (int i = 0; i < 16; ++i) { int t = ws[i]; ws[i] = run; run += t; }
    }
    __syncthreads();
    int excl = ws[wid] + incl - v;
    if (tid < NB) { base[tid] = excl; cursor[tid] = excl; }
    if (tid == 0) base[NB] = E;
}

// --- pass 3: scatter edges into bucket-sorted packed keys (dl<<20 | src) ----
__global__ __launch_bounds__(256) void bucket_scatter(
    const int* __restrict__ src, const int* __restrict__ dst,
    int* __restrict__ cursor, unsigned int* __restrict__ bkey, int E, int NB) {
    __shared__ int h[1024];
    __shared__ int rb[1024];
    const int CH = 2048;
    for (int c0 = blockIdx.x * CH; c0 < E; c0 += gridDim.x * CH) {
        int cend = c0 + CH < E ? c0 + CH : E;
        for (int j = threadIdx.x; j < NB; j += 256) h[j] = 0;
        __syncthreads();
        for (int i = c0 + threadIdx.x; i < cend; i += 256)
            atomicAdd(&h[dst[i] >> 7], 1);
        __syncthreads();
        for (int j = threadIdx.x; j < NB; j += 256) {
            int c = h[j];
            rb[j] = c ? atomicAdd(&cursor[j], c) : 0;
            h[j] = 0;
        }
        __syncthreads();
        for (int i = c0 + threadIdx.x; i < cend; i += 256) {
            int d = dst[i];
            int b = d >> 7;
            int p = rb[b] + atomicAdd(&h[b], 1);
            bkey[p] = ((unsigned int)(d & 127) << 20) | (unsigned int)src[i];
        }
        __syncthreads();
    }
}

// --- pass 4: per-bucket CSR finalize: rowptr, dinv, ssrc --------------------
__global__ __launch_bounds__(256) void bucket_finalize(
    const int* __restrict__ base, const unsigned int* __restrict__ bkey,
    int* __restrict__ rowptr, int* __restrict__ ssrc,
    float* __restrict__ dinv, int N, int NB, int E) {
    __shared__ int cnt[128];
    __shared__ int cur[128];
    __shared__ int w0sum;
    const int tid = threadIdx.x;
    const int lane = tid & 63;
    for (int b = blockIdx.x; b < NB; b += gridDim.x) {
        const int s = base[b], e = base[b + 1];
        const int d0 = b << 7;
        const int w = (N - d0 < 128) ? (N - d0) : 128;
        if (tid < 128) cnt[tid] = 0;
        __syncthreads();
        for (int i = s + tid; i < e; i += 256) atomicAdd(&cnt[bkey[i] >> 20], 1);
        __syncthreads();
        int v = (tid < 128) ? cnt[tid] : 0;
        int incl = v;
#pragma unroll
        for (int off = 1; off < 64; off <<= 1) {
            int t = __shfl_up(incl, off);
            if (lane >= off) incl += t;
        }
        if (tid == 63) w0sum = incl;
        __syncthreads();
        int excl = incl - v + ((tid >= 64 && tid < 128) ? w0sum : 0);
        if (tid < 128) cur[tid] = s + excl;
        if (tid < w) {
            rowptr[d0 + tid] = s + excl;
            dinv[d0 + tid] = rsqrtf((float)(v + 1));   // +1 self loop
        }
        __syncthreads();
        for (int i = s + tid; i < e; i += 256) {
            unsigned int k = bkey[i];
            int p = atomicAdd(&cur[k >> 20], 1);
            ssrc[p] = (int)(k & 0xFFFFFu);
        }
        __syncthreads();
    }
    if (blockIdx.x == 0 && tid == 0) rowptr[N] = E;
}

// --- dense transform + dinv pre-scale (readlane broadcast, row-major):
//   hs[row,l] = dinv[row] * sum_k in[row,k] * W[k,l]
template <int K>
__global__ __launch_bounds__(256) void gemm_hs(
    const float* __restrict__ in, const float* __restrict__ W,
    const float* __restrict__ dinv, float* __restrict__ hs, int n) {
    const int lane = threadIdx.x & 63;
    const int gw = blockIdx.x * (blockDim.x >> 6) + (threadIdx.x >> 6);
    const int nw = gridDim.x * (blockDim.x >> 6);

    float wreg[K];
#pragma unroll
    for (int k = 0; k < K; ++k) wreg[k] = W[k * 64 + lane];

    for (int row = gw; row < n; row += nw) {
        float xv0 = in[(size_t)row * K + lane];
        float xv1 = 0.f;
        if (K == 128) xv1 = in[(size_t)row * K + 64 + lane];
        float a0 = 0.f, a1 = 0.f, a2 = 0.f, a3 = 0.f;
#pragma unroll
        for (int k = 0; k < 64; k += 4) {
            a0 = fmaf(readlane_f(xv0, k + 0), wreg[k + 0], a0);
            a1 = fmaf(readlane_f(xv0, k + 1), wreg[k + 1], a1);
            a2 = fmaf(readlane_f(xv0, k + 2), wreg[k + 2], a2);
            a3 = fmaf(readlane_f(xv0, k + 3), wreg[k + 3], a3);
        }
        if (K == 128) {
#pragma unroll
            for (int k = 0; k < 64; k += 4) {
                a0 = fmaf(readlane_f(xv1, k + 0), wreg[64 + k + 0], a0);
                a1 = fmaf(readlane_f(xv1, k + 1), wreg[64 + k + 1], a1);
                a2 = fmaf(readlane_f(xv1, k + 2), wreg[64 + k + 2], a2);
                a3 = fmaf(readlane_f(xv1, k + 3), wreg[64 + k + 3], a3);
            }
        }
        float acc = (a0 + a1) + (a2 + a3);
        hs[(size_t)row * 64 + lane] = dinv[row] * acc;
    }
}

// --- aggregation with wide masked gathers (R11 exact): wave = dst row,
//     64 lanes = 4 edges (g) x 16 float4-chunks (c); no serial tail.
__global__ __launch_bounds__(256) void csr_agg_f4(
    const float* __restrict__ hs, const int* __restrict__ rowptr,
    const int* __restrict__ ssrc, const float* __restrict__ dinv,
    const float* __restrict__ b, float* __restrict__ xact, int N) {
    const int lane = threadIdx.x & 63;
    const int g = lane >> 4;         // edge slot 0..3
    const int c = lane & 15;         // float4 chunk 0..15
    const int w = blockIdx.x * 4 + (threadIdx.x >> 6);
    const int nw = gridDim.x * 4;
    const float4 bl = ((const float4*)b)[c];

    for (int d = w; d < N; d += nw) {
        int e = __builtin_amdgcn_readfirstlane(rowptr[d]);
        const int end = __builtin_amdgcn_readfirstlane(rowptr[d + 1]);
        const int last = end - 1;
        float4 a0 = make_float4(0.f, 0.f, 0.f, 0.f), a1 = a0;
        if (g == 0) a0 = ((const float4*)(hs + (size_t)d * 64))[c];  // self loop
        for (; e < end; e += 16) {
            int i0 = e + g, i1 = e + 4 + g, i2 = e + 8 + g, i3 = e + 12 + g;
            float m0 = i0 < end ? 1.f : 0.f;
            float m1 = i1 < end ? 1.f : 0.f;
            float m2 = i2 < end ? 1.f : 0.f;
            float m3 = i3 < end ? 1.f : 0.f;
            i0 = i0 < last ? i0 : last;
            i1 = i1 < last ? i1 : last;
            i2 = i2 < last ? i2 : last;
            i3 = i3 < last ? i3 : last;
            int s0 = __builtin_nontemporal_load(ssrc + i0);
            int s1 = __builtin_nontemporal_load(ssrc + i1);
            int s2 = __builtin_nontemporal_load(ssrc + i2);
            int s3 = __builtin_nontemporal_load(ssrc + i3);
            float4 v0 = ((const float4*)(hs + (size_t)s0 * 64))[c];
            float4 v1 = ((const float4*)(hs + (size_t)s1 * 64))[c];
            float4 v2 = ((const float4*)(hs + (size_t)s2 * 64))[c];
            float4 v3 = ((const float4*)(hs + (size_t)s3 * 64))[c];
            a0.x = fmaf(m0, v0.x, a0.x); a0.y = fmaf(m0, v0.y, a0.y);
            a0.z = fmaf(m0, v0.z, a0.z); a0.w = fmaf(m0, v0.w, a0.w);
            a1.x = fmaf(m1, v1.x, a1.x); a1.y = fmaf(m1, v1.y, a1.y);
            a1.z = fmaf(m1, v1.z, a1.z); a1.w = fmaf(m1, v1.w, a1.w);
            a0.x = fmaf(m2, v2.x, a0.x); a0.y = fmaf(m2, v2.y, a0.y);
            a0.z = fmaf(m2, v2.z, a0.z); a0.w = fmaf(m2, v2.w, a0.w);
            a1.x = fmaf(m3, v3.x, a1.x); a1.y = fmaf(m3, v3.y, a1.y);
            a1.z = fmaf(m3, v3.z, a1.z); a1.w = fmaf(m3, v3.w, a1.w);
        }
        float4 acc = make_float4(a0.x + a1.x, a0.y + a1.y, a0.z + a1.z, a0.w + a1.w);
        // reduce over the 4 edge groups (lane ^16, ^32)
        acc.x += __shfl_xor(acc.x, 16); acc.y += __shfl_xor(acc.y, 16);
        acc.z += __shfl_xor(acc.z, 16); acc.w += __shfl_xor(acc.w, 16);
        acc.x += __shfl_xor(acc.x, 32); acc.y += __shfl_xor(acc.y, 32);
        acc.z += __shfl_xor(acc.z, 32); acc.w += __shfl_xor(acc.w, 32);
        const float di = dinv[d];
        float4 y;
        y.x = fmaf(di, acc.x, bl.x); y.y = fmaf(di, acc.y, bl.y);
        y.z = fmaf(di, acc.z, bl.z); y.w = fmaf(di, acc.w, bl.w);
        y.x = y.x >= 0.f ? y.x : 0.2f * y.x;
        y.y = y.y >= 0.f ? y.y : 0.2f * y.y;
        y.z = y.z >= 0.f ? y.z : 0.2f * y.z;
        y.w = y.w >= 0.f ? y.w : 0.2f * y.w;
        if (g == 0) ((float4*)(xact + (size_t)d * 64))[c] = y;
    }
}

// --- final layer gemm: pre-activated x -> W5[64,4] -> dinv scale ------------
__global__ __launch_bounds__(256) void gemm4_hs(
    const float* __restrict__ xact, const float* __restrict__ W,  // [64,4]
    const float* __restrict__ dinv, float* __restrict__ hs4, int n) {
    int i = blockIdx.x * blockDim.x + threadIdx.x;
    int stride = gridDim.x * blockDim.x;
    for (; i < n; i += stride) {
        const float4* xr = (const float4*)(xact + (size_t)i * 64);
        float a0 = 0.f, a1 = 0.f, a2 = 0.f, a3 = 0.f;
#pragma unroll
        for (int k4 = 0; k4 < 16; ++k4) {
            float4 xv = xr[k4];
            int k = k4 * 4;
            a0 = fmaf(xv.x, W[(k + 0) * 4 + 0], a0); a1 = fmaf(xv.x, W[(k + 0) * 4 + 1], a1);
            a2 = fmaf(xv.x, W[(k + 0) * 4 + 2], a2); a3 = fmaf(xv.x, W[(k + 0) * 4 + 3], a3);
            a0 = fmaf(xv.y, W[(k + 1) * 4 + 0], a0); a1 = fmaf(xv.y, W[(k + 1) * 4 + 1], a1);
            a2 = fmaf(xv.y, W[(k + 1) * 4 + 2], a2); a3 = fmaf(xv.y, W[(k + 1) * 4 + 3], a3);
            a0 = fmaf(xv.z, W[(k + 2) * 4 + 0], a0); a1 = fmaf(xv.z, W[(k + 2) * 4 + 1], a1);
            a2 = fmaf(xv.z, W[(k + 2) * 4 + 2], a2); a3 = fmaf(xv.z, W[(k + 2) * 4 + 3], a3);
            a0 = fmaf(xv.w, W[(k + 3) * 4 + 0], a0); a1 = fmaf(xv.w, W[(k + 3) * 4 + 1], a1);
            a2 = fmaf(xv.w, W[(k + 3) * 4 + 2], a2); a3 = fmaf(xv.w, W[(k + 3) * 4 + 3], a3);
        }
        float di = dinv[i];
        ((float4*)hs4)[i] = make_float4(di * a0, di * a1, di * a2, di * a3);
    }
}

// --- final aggregation over pre-scaled hs4: out = b + dinv[d]*(self + sum) --
__global__ __launch_bounds__(256) void csr_agg4(
    const float* __restrict__ hs4, const int* __restrict__ rowptr,
    const int* __restrict__ ssrc, const float* __restrict__ dinv,
    const float* __restrict__ b, float* __restrict__ out, int n) {
    int i = blockIdx.x * blockDim.x + threadIdx.x;
    int stride = gridDim.x * blockDim.x;
    float b0 = b[0], b1 = b[1], b2 = b[2], b3 = b[3];
    for (; i < n; i += stride) {
        float4 hv = ((const float4*)hs4)[i];
        float a0 = hv.x, a1 = hv.y, a2 = hv.z, a3 = hv.w;   // self loop
        int e = rowptr[i], end = rowptr[i + 1];
        for (; e < end; ++e) {
            int s = ssrc[e];
            float4 v = ((const float4*)hs4)[s];
            a0 += v.x; a1 += v.y; a2 += v.z; a3 += v.w;
        }
        float di = dinv[i];
        ((float4*)out)[i] = make_float4(fmaf(di, a0, b0), fmaf(di, a1, b1),
                                        fmaf(di, a2, b2), fmaf(di, a3, b3));
    }
}

static inline size_t al64(size_t x) { return (x + 63) & ~(size_t)63; }

extern "C" void kernel_launch(void* const* d_in, const int* in_sizes, int n_in,
                              void* d_out, int out_size, void* d_ws, size_t ws_size,
                              hipStream_t stream) {
    const float* x  = (const float*)d_in[0];
    const int* ei   = (const int*)d_in[1];
    const float* W0 = (const float*)d_in[2];
    const float* b0 = (const float*)d_in[3];
    const float* W1 = (const float*)d_in[4];
    const float* b1 = (const float*)d_in[5];
    const float* W2 = (const float*)d_in[6];
    const float* b2 = (const float*)d_in[7];
    const float* W3 = (const float*)d_in[8];
    const float* b3 = (const float*)d_in[9];
    const float* W4 = (const float*)d_in[10];
    const float* b4 = (const float*)d_in[11];
    const float* W5 = (const float*)d_in[12];
    const float* b5 = (const float*)d_in[13];

    const int N = in_sizes[0] / 128;
    const int E = in_sizes[1] / 2;
    const int* src  = ei;       // edge_index[0] = message sources
    const int* dstp = ei + E;   // edge_index[1] = aggregation targets
    const int NB = (N + 127) >> 7;   // dst buckets of 128 ids (NB <= 1024)

    float* ws = (float*)d_ws;
    size_t off = 0;
    int*   rowptr = (int*)(ws + off);   off += al64((size_t)N + 1);
    float* dinv   = ws + off;           off += al64((size_t)N);
    int*   ssrc   = (int*)(ws + off);   off += al64((size_t)E);
    float* bufA   = ws + off;           off += (size_t)64 * N;
    float* bufB   = ws + off;

    // build temps alias into bufA (released before layer 0 writes bufA)
    int* ghist = (int*)bufA;                        // [1024]
    int* bbase = ghist + 1024;                      // [NB+1]
    int* bcur  = bbase + 1088;                      // [NB]
    unsigned int* bkey = (unsigned int*)(bufA + 4096);  // [E] packed dl<<20|src

    // ---- graph build (bucketed counting sort, packed keys) ----
    hipMemsetAsync(ghist, 0, 1024 * sizeof(int), stream);
    bucket_hist<<<784, 256, 0, stream>>>(dstp, ghist, E, NB);
    bucket_scan<<<1, 1024, 0, stream>>>(ghist, bbase, bcur, NB, E);
    bucket_scatter<<<782, 256, 0, stream>>>(src, dstp, bcur, bkey, E, NB);
    bucket_finalize<<<NB, 256, 0, stream>>>(bbase, bkey, rowptr, ssrc, dinv, N, NB, E);

    const int AGG_BLOCKS = 4096;

    // ---- layer 0: x[N,128] -> hs0 ----
    gemm_hs<128><<<2048, 256, 0, stream>>>(x, W0, dinv, bufA, N);
    csr_agg_f4<<<AGG_BLOCKS, 256, 0, stream>>>(bufA, rowptr, ssrc, dinv, b0, bufB, N);

    // ---- layers 1-4 (xact in bufB -> hs in bufA -> xact in bufB) ----
    const float* Ws[4] = {W1, W2, W3, W4};
    const float* bs[4] = {b1, b2, b3, b4};
    for (int l = 0; l < 4; ++l) {
        gemm_hs<64><<<2048, 256, 0, stream>>>(bufB, Ws[l], dinv, bufA, N);
        csr_agg_f4<<<AGG_BLOCKS, 256, 0, stream>>>(bufA, rowptr, ssrc, dinv, bs[l], bufB, N);
    }

    // ---- layer 5: xact -> hs4[N,4] -> out ----
    gemm4_hs<<<1024, 256, 0, stream>>>(bufB, W5, dinv, bufA, N);
    csr_agg4<<<1024, 256, 0, stream>>>(bufA, rowptr, ssrc, dinv, b5, (float*)d_out, N);
}